// Round 4
// baseline (195.957 us; speedup 1.0000x reference)
//
#include <hip/hip_runtime.h>

#define TT   256    // timesteps
#define FF   23     // lab features
#define HH   100    // hidden
#define NROW 4      // batch rows per workgroup
#define NTHR 448    // 7 waves, all compute
#define NWG  256    // 1024 / NROW -> one wg per CU

typedef unsigned int  u32;
typedef unsigned short u16;
typedef __attribute__((ext_vector_type(8))) short short8;  // 8 bf16 in 4 VGPRs
typedef __attribute__((ext_vector_type(4))) float f32x4;

__device__ __forceinline__ u16 f2bf(float f){           // RTNE f32->bf16
  u32 u = __float_as_uint(f);
  u += 0x7fffu + ((u >> 16) & 1u);
  return (u16)(u >> 16);
}
__device__ __forceinline__ float fsig(float x){
  return __builtin_amdgcn_rcpf(1.0f + __expf(-x));
}
__device__ __forceinline__ float ftanh(float x){
  return 1.0f - 2.0f * __builtin_amdgcn_rcpf(__expf(2.0f * x) + 1.0f);
}

// LDS layouts (bf16):
//  h/c: idx(b,k) = (k>>5)*128 + b*32 + ((k>>3)&3)*8 + (k&7)   [kf][b][q4][i]
//  x:   sXall[t*128 + b*32 + k]  (entire sequence staged; k=24..27 carry the
//       h[96..99] fold, written each step by wave 6)
// Batch row b sits at MFMA tile-row 4b -> C/D reg 0 of every lane is real.
// A-frag read (lane q4,nl with nl%4==0): 8 contiguous shorts at
//   kf*128 + (nl>>2)*32 + q4*8  -> 16 lanes span 256B contiguous, conflict-free.

__global__ __launch_bounds__(NTHR, 2) void tlstm5(
    const float* __restrict__ x_lab,  const float* __restrict__ t_lab,
    const float* __restrict__ x_state,const float* __restrict__ W_x,
    const float* __restrict__ W_h,    const float* __restrict__ b_lstm,
    const float* __restrict__ W_d,    const float* __restrict__ b_d,
    const float* __restrict__ W_state,const float* __restrict__ b_state,
    const float* __restrict__ W_fc,   const float* __restrict__ b_fc,
    float* __restrict__ out)
{
  __shared__ __align__(16) short sXall[TT * 128]; // 64 KB: x for ALL steps
  __shared__ __align__(16) short sHC[2][2][512];  // [buf][h=0/c=1]
  __shared__ __align__(16) float sDec[TT * NROW]; // [t*4 + b]
  __shared__ __align__(16) float sHF[NROW][128];  // fp32 h_final

  const int tid  = threadIdx.x;
  const int lane = tid & 63;
  const int w    = tid >> 6;        // wave 0..6
  const int nl   = lane & 15;
  const int q4   = lane >> 4;
  const int b0   = blockIdx.x * NROW;
  const int j    = w * 16 + nl;     // hidden column (j<=111; real <100)
  const bool jr  = (j < HH);

  // ---- zero h/c state buffers ----
  for (int i = tid; i < 1024; i += NTHR) ((u32*)sHC)[i] = 0u;

  // ---- stage ENTIRE x sequence (bf16, frag layout, pads zeroed) ----
  for (int e = tid; e < TT * 128; e += NTHR) {
    int t = e >> 7, inner = e & 127, r = inner >> 5, f = inner & 31;
    float x = (f < FF) ? x_lab[((b0 + r)*TT + t)*FF + f] : 0.f;
    sXall[e] = (short)f2bf(x);
  }
  // ---- decay table ----
  for (int e = tid; e < TT * NROW; e += NTHR) {
    int t = e >> 2, r = e & 3;
    sDec[e] = 1.0f / logf(2.718281828459045f + t_lab[(b0 + r)*TT + t]);
  }

  // ---- persistent weight fragments (B-operand: col=nl -> j, k=kf*32+q4*8+i) ----
  short8 wh[4][3], wd[4], wx[4];
#pragma unroll
  for (int g = 0; g < 4; ++g)
#pragma unroll
    for (int kf = 0; kf < 3; ++kf) {
      short8 v;
#pragma unroll
      for (int i = 0; i < 8; ++i) {
        int k = kf*32 + q4*8 + i;                 // k <= 95: always real
        v[i] = (short)(jr ? f2bf(W_h[k*400 + g*HH + j]) : 0);
      }
      wh[g][kf] = v;
    }
#pragma unroll
  for (int kf = 0; kf < 4; ++kf) {
    short8 v;
#pragma unroll
    for (int i = 0; i < 8; ++i) {
      int k = kf*32 + q4*8 + i;
      v[i] = (short)((k < HH && jr) ? f2bf(W_d[k*HH + j]) : 0);
    }
    wd[kf] = v;
  }
#pragma unroll
  for (int g = 0; g < 4; ++g) {
    short8 v;
#pragma unroll
    for (int i = 0; i < 8; ++i) {
      int k = q4*8 + i;
      float x = 0.f;
      if (jr) {
        if (k < FF)                 x = W_x[k*400 + g*HH + j];
        else if (k >= 24 && k < 28) x = W_h[(96 + (k-24))*400 + g*HH + j]; // h-fold
      }
      v[i] = (short)f2bf(x);
    }
    wx[g] = v;
  }

  float bl[4], bd;
#pragma unroll
  for (int g = 0; g < 4; ++g) bl[g] = jr ? b_lstm[g*HH + j] : 0.f;
  bd = jr ? b_d[j] : 0.f;

  __syncthreads();

  const bool rdr  = ((nl & 3) == 0);          // A-frag reader lanes
  const int rbase = (nl >> 2)*32 + q4*8;
  const int widx  = (j >> 5)*128 + q4*32 + ((j >> 3) & 3)*8 + (j & 7);

  short8 ha[3] = {}, ca[4] = {}, xa = {};     // stay 0 in non-reader lanes
  float cm = 0.f;                              // fp32 master cell (b=q4, col j)
  float hl = 0.f;

  const f32x4 zv = {0.f, 0.f, 0.f, 0.f};

  for (int t = 0; t < TT; ++t) {
    const short* hb = sHC[t & 1][0];
    const short* cb = sHC[t & 1][1];
    if (rdr) {
      xa = *(const short8*)(sXall + t*128 + rbase);
#pragma unroll
      for (int kf = 0; kf < 4; ++kf) ca[kf] = *(const short8*)(cb + kf*128 + rbase);
#pragma unroll
      for (int kf = 0; kf < 3; ++kf) ha[kf] = *(const short8*)(hb + kf*128 + rbase);
    }
    float dec = sDec[t*4 + q4];

    // gates: x-part first (independent of h/c reads), then treed h-chain
    f32x4 a0[4], a1[4];
#pragma unroll
    for (int g = 0; g < 4; ++g) {
      f32x4 b = {bl[g], bl[g], bl[g], bl[g]};
      a0[g] = __builtin_amdgcn_mfma_f32_16x16x32_bf16(xa, wx[g], b, 0, 0, 0);
    }
    // c @ W_d as two 2-deep chains
    f32x4 d0 = {bd, bd, bd, bd}, d1 = zv;
    d0 = __builtin_amdgcn_mfma_f32_16x16x32_bf16(ca[0], wd[0], d0, 0, 0, 0);
    d1 = __builtin_amdgcn_mfma_f32_16x16x32_bf16(ca[1], wd[1], d1, 0, 0, 0);
    d0 = __builtin_amdgcn_mfma_f32_16x16x32_bf16(ca[2], wd[2], d0, 0, 0, 0);
    d1 = __builtin_amdgcn_mfma_f32_16x16x32_bf16(ca[3], wd[3], d1, 0, 0, 0);
#pragma unroll
    for (int g = 0; g < 4; ++g) {
      a1[g] = __builtin_amdgcn_mfma_f32_16x16x32_bf16(ha[0], wh[g][0], zv,    0, 0, 0);
      a0[g] = __builtin_amdgcn_mfma_f32_16x16x32_bf16(ha[1], wh[g][1], a0[g], 0, 0, 0);
      a1[g] = __builtin_amdgcn_mfma_f32_16x16x32_bf16(ha[2], wh[g][2], a1[g], 0, 0, 0);
    }

    // ---- pointwise (C/D reg 0 = batch row q4) ----
    float cs   = ftanh(d0[0] + d1[0]);
    float cadj = cm - cs + cs*dec;
    float ig = fsig (a0[0][0] + a1[0][0]);
    float fg = fsig (a0[1][0] + a1[1][0]);
    float gg = ftanh(a0[2][0] + a1[2][0]);
    float og = fsig (a0[3][0] + a1[3][0]);
    float cnv = fg*cadj + ig*gg;
    cm = cnv;
    float hv = og*ftanh(cnv);
    hl = hv;

    short* hn = sHC[(t + 1) & 1][0];
    short* cn = sHC[(t + 1) & 1][1];
    hn[widx] = (short)f2bf(hv);
    cn[widx] = (short)f2bf(cnv);
    if (w == 6 && nl < 4 && t + 1 < TT)        // h[96..99] -> x-frag k=24..27
      sXall[(t + 1)*128 + q4*32 + 24 + nl] = (short)f2bf(hv);

    __syncthreads();
  }

  // ---- epilogue ----
  sHF[q4][j] = hl;
  __syncthreads();

  if (tid < NROW) {
    const int bg = b0 + tid;
    float y0 = b_fc[0], y1 = b_fc[1];
    for (int k = 0; k < HH; ++k) {
      float hv = sHF[tid][k];
      y0 += hv * W_fc[2*k];
      y1 += hv * W_fc[2*k + 1];
    }
#pragma unroll
    for (int k = 0; k < 20; ++k) {
      float a = b_state[k];
#pragma unroll
      for (int s = 0; s < 6; ++s) a += x_state[bg*6 + s] * W_state[s*20 + k];
      y0 += a * W_fc[2*(HH + k)];
      y1 += a * W_fc[2*(HH + k) + 1];
    }
    float m = fmaxf(y0, y1);
    float e0 = __expf(y0 - m), e1 = __expf(y1 - m);
    float inv = 1.0f / (e0 + e1);
    out[bg*2 + 0] = e0 * inv;
    out[bg*2 + 1] = e1 * inv;
  }
}

extern "C" void kernel_launch(void* const* d_in, const int* in_sizes, int n_in,
                              void* d_out, int out_size, void* d_ws, size_t ws_size,
                              hipStream_t stream) {
  const float* x_lab   = (const float*)d_in[0];
  const float* t_lab   = (const float*)d_in[1];
  const float* x_state = (const float*)d_in[2];
  const float* W_x     = (const float*)d_in[3];
  const float* W_h     = (const float*)d_in[4];
  const float* b_lstm  = (const float*)d_in[5];
  const float* W_d     = (const float*)d_in[6];
  const float* b_d     = (const float*)d_in[7];
  const float* W_state = (const float*)d_in[8];
  const float* b_state = (const float*)d_in[9];
  const float* W_fc    = (const float*)d_in[10];
  const float* b_fc    = (const float*)d_in[11];
  float* outp = (float*)d_out;

  hipLaunchKernelGGL(tlstm5, dim3(NWG), dim3(NTHR), 0, stream,
                     x_lab, t_lab, x_state, W_x, W_h, b_lstm, W_d, b_d,
                     W_state, b_state, W_fc, b_fc, outp);
}